// Round 1
// baseline (375.041 us; speedup 1.0000x reference)
//
#include <hip/hip_runtime.h>
#include <hip/hip_bf16.h>
#include <stdint.h>

// MultiHeadAttention fused forward, MI355X/gfx950.
// B=4, S=2048, H=16, hd=64, D=1024. fp32 in/out, bf16 MFMA internally.

typedef __attribute__((ext_vector_type(8))) __bf16 bf16x8;
typedef __attribute__((ext_vector_type(4))) float f32x4;

#define AS_G __attribute__((address_space(1)))
#define AS_L __attribute__((address_space(3)))

__device__ __forceinline__ void gload_lds16(const void* g, void* s) {
  __builtin_amdgcn_global_load_lds((const AS_G void*)g, (AS_L void*)s, 16, 0, 0);
}

// ---------------------------------------------------------------- converts
__global__ void cvt_bf16_kernel(const float* __restrict__ in,
                                __bf16* __restrict__ out, int n8) {
  int i = blockIdx.x * blockDim.x + threadIdx.x;
  if (i >= n8) return;
  float4 a = ((const float4*)in)[i * 2];
  float4 b = ((const float4*)in)[i * 2 + 1];
  union { __bf16 h[8]; int4 v; } u;
  u.h[0] = (__bf16)a.x; u.h[1] = (__bf16)a.y; u.h[2] = (__bf16)a.z; u.h[3] = (__bf16)a.w;
  u.h[4] = (__bf16)b.x; u.h[5] = (__bf16)b.y; u.h[6] = (__bf16)b.z; u.h[7] = (__bf16)b.w;
  ((int4*)out)[i] = u.v;
}

// out[n*K + k] = (bf16) in[k*N + n]
__global__ void cvt_T_kernel(const float* __restrict__ in,
                             __bf16* __restrict__ out, int K, int N) {
  __shared__ float tile[32][33];
  int bx = blockIdx.x;  // along N
  int by = blockIdx.y;  // along K
  int tx = threadIdx.x & 31, ty = threadIdx.x >> 5;  // 32 x 8
#pragma unroll
  for (int i = 0; i < 32; i += 8)
    tile[ty + i][tx] = in[(size_t)(by * 32 + ty + i) * N + bx * 32 + tx];
  __syncthreads();
#pragma unroll
  for (int i = 0; i < 32; i += 8)
    out[(size_t)(bx * 32 + ty + i) * K + by * 32 + tx] = (__bf16)tile[tx][ty + i];
}

// ---------------------------------------------------------------- GEMM
// C[M,1024-chunked-N] = A[M,1024] @ Bt[N,1024]^T   (K = 1024 for both GEMMs)
// MODE 0: QKV projection epilogue (scatter Q*0.125 / K / V-transposed, +bias)
// MODE 1: output projection epilogue (fp32 out, +bias)
template <int MODE>
__global__ __launch_bounds__(256) void gemm_bt(
    const __bf16* __restrict__ A, const __bf16* __restrict__ Bt,
    const float* __restrict__ bias,
    __bf16* __restrict__ Qb, __bf16* __restrict__ Kb, __bf16* __restrict__ Vtb,
    float* __restrict__ Out) {
  __shared__ __bf16 As[128 * 32];
  __shared__ __bf16 Bs[128 * 32];
  const int tid = threadIdx.x;
  const int wave = tid >> 6, lane = tid & 63;
  const int lhi = lane >> 4, llo = lane & 15;
  const int wm = wave >> 1, wn = wave & 1;
  const int m0 = blockIdx.y * 128, n0 = blockIdx.x * 128;

  const int srow = lane >> 2;         // 0..15 within a 16-row issue
  const int scol = (lane & 3) * 8;    // element column (x8 bf16 = 16B)
  const __bf16* Ag0 = A + (size_t)(m0 + (wave * 2 + 0) * 16 + srow) * 1024 + scol;
  const __bf16* Ag1 = A + (size_t)(m0 + (wave * 2 + 1) * 16 + srow) * 1024 + scol;
  const __bf16* Bg0 = Bt + (size_t)(n0 + (wave * 2 + 0) * 16 + srow) * 1024 + scol;
  const __bf16* Bg1 = Bt + (size_t)(n0 + (wave * 2 + 1) * 16 + srow) * 1024 + scol;
  __bf16* As0 = As + (wave * 2 + 0) * 512;
  __bf16* As1 = As + (wave * 2 + 1) * 512;
  __bf16* Bs0 = Bs + (wave * 2 + 0) * 512;
  __bf16* Bs1 = Bs + (wave * 2 + 1) * 512;

  f32x4 acc[4][4];
#pragma unroll
  for (int m = 0; m < 4; ++m)
#pragma unroll
    for (int n = 0; n < 4; ++n) acc[m][n] = (f32x4){0.f, 0.f, 0.f, 0.f};

  for (int k0 = 0; k0 < 1024; k0 += 32) {
    gload_lds16(Ag0 + k0, As0);
    gload_lds16(Ag1 + k0, As1);
    gload_lds16(Bg0 + k0, Bs0);
    gload_lds16(Bg1 + k0, Bs1);
    __syncthreads();
    bf16x8 af[4], bfr[4];
#pragma unroll
    for (int i = 0; i < 4; ++i)
      af[i] = *(const bf16x8*)&As[(wm * 64 + i * 16 + llo) * 32 + lhi * 8];
#pragma unroll
    for (int i = 0; i < 4; ++i)
      bfr[i] = *(const bf16x8*)&Bs[(wn * 64 + i * 16 + llo) * 32 + lhi * 8];
#pragma unroll
    for (int m = 0; m < 4; ++m)
#pragma unroll
      for (int n = 0; n < 4; ++n)
        acc[m][n] = __builtin_amdgcn_mfma_f32_16x16x32_bf16(af[m], bfr[n],
                                                            acc[m][n], 0, 0, 0);
    __syncthreads();
  }

#pragma unroll
  for (int ni = 0; ni < 4; ++ni) {
    const int col = n0 + wn * 64 + ni * 16 + llo;
    const float bv = bias[col];
    if (MODE == 0) {
      const int h = col / 192, rem = col % 192;
#pragma unroll
      for (int mi = 0; mi < 4; ++mi) {
        const int row0 = m0 + wm * 64 + mi * 16 + lhi * 4;
        const int b = row0 >> 11;
        const int s0 = row0 & 2047;
        const int bh = b * 16 + h;
        f32x4 v = acc[mi][ni];
        if (rem < 64) {
#pragma unroll
          for (int r = 0; r < 4; ++r)
            Qb[((size_t)bh * 2048 + s0 + r) * 64 + rem] =
                (__bf16)((v[r] + bv) * 0.125f);
        } else if (rem < 128) {
#pragma unroll
          for (int r = 0; r < 4; ++r)
            Kb[((size_t)bh * 2048 + s0 + r) * 64 + (rem - 64)] = (__bf16)(v[r] + bv);
        } else {
          union { __bf16 h4[4]; int2 v2; } u;
#pragma unroll
          for (int r = 0; r < 4; ++r) u.h4[r] = (__bf16)(v[r] + bv);
          *(int2*)&Vtb[((size_t)bh * 64 + (rem - 128)) * 2048 + s0] = u.v2;
        }
      }
    } else {
#pragma unroll
      for (int mi = 0; mi < 4; ++mi) {
        const int row0 = m0 + wm * 64 + mi * 16 + lhi * 4;
        f32x4 v = acc[mi][ni];
#pragma unroll
        for (int r = 0; r < 4; ++r)
          Out[(size_t)(row0 + r) * 1024 + col] = v[r] + bv;
      }
    }
  }
}

// ---------------------------------------------------------------- attention
// grid (32 qtiles, 64 bh). 4 waves x 16 q rows. KV tiles of 64, causal.
__global__ __launch_bounds__(256) void attn_kernel(
    const __bf16* __restrict__ Q, const __bf16* __restrict__ K,
    const __bf16* __restrict__ Vt, __bf16* __restrict__ vals) {
  __shared__ __bf16 Ks[64 * 64];
  __shared__ __bf16 Vs[64 * 64];       // V^T tile: [d=64][kv=64]
  __shared__ __bf16 Ps[4][16 * 72];    // per-wave P tile, stride 72 (pad)
  const int tid = threadIdx.x;
  const int wave = tid >> 6, lane = tid & 63;
  const int lhi = lane >> 4, llo = lane & 15;
  const int qt = blockIdx.x, bh = blockIdx.y;
  const int q0 = qt * 64;

  const int qrow = q0 + wave * 16 + llo;
  const __bf16* qp = Q + ((size_t)bh * 2048 + qrow) * 64 + lhi * 8;
  const bf16x8 qf0 = *(const bf16x8*)qp;
  const bf16x8 qf1 = *(const bf16x8*)(qp + 32);

  f32x4 accO[4];
#pragma unroll
  for (int n = 0; n < 4; ++n) accO[n] = (f32x4){0.f, 0.f, 0.f, 0.f};
  float mrow[4] = {-3e38f, -3e38f, -3e38f, -3e38f};
  float lrow[4] = {0.f, 0.f, 0.f, 0.f};

  const int nt = qt + 1;
  for (int t = 0; t < nt; ++t) {
    const int kv0 = t * 64;
    // stage K tile [kv=64][d=64] and Vt tile [d=64][kv=64], XOR-swizzled 16B blocks
#pragma unroll
    for (int rep = 0; rep < 2; ++rep) {
      const int u = rep * 256 + tid;
      const int row = u >> 3, blk = u & 7;
      const int sb = (blk ^ (row & 7)) * 8;
      *(int4*)&Ks[row * 64 + sb] =
          *(const int4*)(K + ((size_t)bh * 2048 + kv0 + row) * 64 + blk * 8);
      *(int4*)&Vs[row * 64 + sb] =
          *(const int4*)(Vt + ((size_t)bh * 64 + row) * 2048 + kv0 + blk * 8);
    }
    __syncthreads();

    // S = Q @ K^T  (per wave: 16 q x 64 kv)
    f32x4 s[4];
#pragma unroll
    for (int n = 0; n < 4; ++n) {
      const int krow = n * 16 + llo;
      const bf16x8 k0 = *(const bf16x8*)&Ks[krow * 64 + (lhi ^ (krow & 7)) * 8];
      const bf16x8 k1 = *(const bf16x8*)&Ks[krow * 64 + ((4 + lhi) ^ (krow & 7)) * 8];
      f32x4 a = (f32x4){0.f, 0.f, 0.f, 0.f};
      a = __builtin_amdgcn_mfma_f32_16x16x32_bf16(qf0, k0, a, 0, 0, 0);
      a = __builtin_amdgcn_mfma_f32_16x16x32_bf16(qf1, k1, a, 0, 0, 0);
      s[n] = a;
    }

    const bool diag = (t == qt);
#pragma unroll
    for (int r = 0; r < 4; ++r) {
      const int qg = q0 + wave * 16 + lhi * 4 + r;
      if (diag) {
#pragma unroll
        for (int n = 0; n < 4; ++n)
          if (kv0 + n * 16 + llo > qg) s[n][r] = -3e38f;
      }
      float mx = fmaxf(fmaxf(s[0][r], s[1][r]), fmaxf(s[2][r], s[3][r]));
#pragma unroll
      for (int off = 1; off < 16; off <<= 1) mx = fmaxf(mx, __shfl_xor(mx, off, 64));
      const float mn = fmaxf(mrow[r], mx);
      const float f = __expf(mrow[r] - mn);
      mrow[r] = mn;
      float p[4], sum = 0.f;
#pragma unroll
      for (int n = 0; n < 4; ++n) { p[n] = __expf(s[n][r] - mn); sum += p[n]; }
#pragma unroll
      for (int off = 1; off < 16; off <<= 1) sum += __shfl_xor(sum, off, 64);
      lrow[r] = lrow[r] * f + sum;
#pragma unroll
      for (int n = 0; n < 4; ++n) {
        accO[n][r] *= f;
        Ps[wave][(lhi * 4 + r) * 72 + n * 16 + llo] = (__bf16)p[n];
      }
    }

    // O += P @ V  (A-frag from Ps, B-frag from swizzled Vs)
#pragma unroll
    for (int c = 0; c < 2; ++c) {
      const bf16x8 pa = *(const bf16x8*)&Ps[wave][llo * 72 + c * 32 + lhi * 8];
#pragma unroll
      for (int n = 0; n < 4; ++n) {
        const int vrow = n * 16 + llo;
        const bf16x8 vb =
            *(const bf16x8*)&Vs[vrow * 64 + ((c * 4 + lhi) ^ (vrow & 7)) * 8];
        accO[n] = __builtin_amdgcn_mfma_f32_16x16x32_bf16(pa, vb, accO[n], 0, 0, 0);
      }
    }
    __syncthreads();
  }

#pragma unroll
  for (int r = 0; r < 4; ++r) {
    const float inv = 1.0f / lrow[r];
    const int qg = q0 + wave * 16 + lhi * 4 + r;
    const size_t base = ((size_t)bh * 2048 + qg) * 64;
#pragma unroll
    for (int n = 0; n < 4; ++n)
      vals[base + n * 16 + llo] = (__bf16)(accO[n][r] * inv);
  }
}

// ---------------------------------------------------------------- launch
extern "C" void kernel_launch(void* const* d_in, const int* in_sizes, int n_in,
                              void* d_out, int out_size, void* d_ws, size_t ws_size,
                              hipStream_t stream) {
  const float* x = (const float*)d_in[0];
  const float* Wqkv = (const float*)d_in[1];
  const float* bqkv = (const float*)d_in[2];
  const float* Wo = (const float*)d_in[3];
  const float* bo = (const float*)d_in[4];
  float* out = (float*)d_out;
  char* ws = (char*)d_ws;

  // workspace layout (bytes)
  __bf16* xb  = (__bf16*)(ws);                 // 16 MB (x bf16; reused as vals)
  __bf16* Wqt = (__bf16*)(ws + 16777216);      // 6 MB  (W_qkv^T bf16 [3072][1024])
  __bf16* Wot = (__bf16*)(ws + 23068672);      // 2 MB  (W_o^T bf16 [1024][1024])
  __bf16* Qb  = (__bf16*)(ws + 25165824);      // 16 MB ([BH, S, 64], pre-scaled 1/8)
  __bf16* Kb  = (__bf16*)(ws + 41943040);      // 16 MB ([BH, S, 64])
  __bf16* Vtb = (__bf16*)(ws + 58720256);      // 16 MB ([BH, 64, S])
  __bf16* vals = xb;                           // attention output (scrambled matrix)

  cvt_bf16_kernel<<<4096, 256, 0, stream>>>(x, xb, 1048576);
  cvt_T_kernel<<<dim3(96, 32), 256, 0, stream>>>(Wqkv, Wqt, 1024, 3072);
  cvt_T_kernel<<<dim3(32, 32), 256, 0, stream>>>(Wo, Wot, 1024, 1024);
  gemm_bt<0><<<dim3(24, 64), 256, 0, stream>>>(xb, Wqt, bqkv, Qb, Kb, Vtb, nullptr);
  attn_kernel<<<dim3(32, 64), 256, 0, stream>>>(Qb, Kb, Vtb, vals);
  gemm_bt<1><<<dim3(8, 64), 256, 0, stream>>>(vals, Wot, bo, nullptr, nullptr, nullptr, out);
}

// Round 2
// 201.655 us; speedup vs baseline: 1.8598x; 1.8598x over previous
//
#include <hip/hip_runtime.h>
#include <hip/hip_bf16.h>
#include <stdint.h>

// MultiHeadAttention fused forward, MI355X/gfx950.
// B=4, S=2048, H=16, hd=64, D=1024. fp32 in/out, bf16 MFMA internally.

typedef __attribute__((ext_vector_type(8))) __bf16 bf16x8;
typedef __attribute__((ext_vector_type(4))) float f32x4;
typedef __attribute__((ext_vector_type(16))) float f32x16;

#define AS_G __attribute__((address_space(1)))
#define AS_L __attribute__((address_space(3)))

__device__ __forceinline__ void gload_lds16(const void* g, void* s) {
  __builtin_amdgcn_global_load_lds((const AS_G void*)g, (AS_L void*)s, 16, 0, 0);
}

__device__ __forceinline__ unsigned cvt_pk_bf16(float lo, float hi) {
  unsigned r;
  asm("v_cvt_pk_bf16_f32 %0, %1, %2" : "=v"(r) : "v"(lo), "v"(hi));
  return r;
}

// ---------------------------------------------------------------- converts
__global__ void cvt_bf16_kernel(const float* __restrict__ in,
                                __bf16* __restrict__ out, int n8) {
  int i = blockIdx.x * blockDim.x + threadIdx.x;
  if (i >= n8) return;
  float4 a = ((const float4*)in)[i * 2];
  float4 b = ((const float4*)in)[i * 2 + 1];
  union { __bf16 h[8]; int4 v; } u;
  u.h[0] = (__bf16)a.x; u.h[1] = (__bf16)a.y; u.h[2] = (__bf16)a.z; u.h[3] = (__bf16)a.w;
  u.h[4] = (__bf16)b.x; u.h[5] = (__bf16)b.y; u.h[6] = (__bf16)b.z; u.h[7] = (__bf16)b.w;
  ((int4*)out)[i] = u.v;
}

// out[n*K + k] = (bf16) in[k*N + n]
__global__ void cvt_T_kernel(const float* __restrict__ in,
                             __bf16* __restrict__ out, int K, int N) {
  __shared__ float tile[32][33];
  int bx = blockIdx.x;  // along N
  int by = blockIdx.y;  // along K
  int tx = threadIdx.x & 31, ty = threadIdx.x >> 5;  // 32 x 8
#pragma unroll
  for (int i = 0; i < 32; i += 8)
    tile[ty + i][tx] = in[(size_t)(by * 32 + ty + i) * N + bx * 32 + tx];
  __syncthreads();
#pragma unroll
  for (int i = 0; i < 32; i += 8)
    out[(size_t)(bx * 32 + ty + i) * K + by * 32 + tx] = (__bf16)tile[tx][ty + i];
}

// ---------------------------------------------------------------- GEMM
// C[M,1024-chunked-N] = A[M,1024] @ Bt[N,1024]^T   (K = 1024 for both GEMMs)
// MODE 0: QKV projection epilogue (scatter Q*0.125 / K / V-transposed, +bias)
// MODE 1: output projection epilogue (fp32 out, +bias)
template <int MODE>
__global__ __launch_bounds__(256) void gemm_bt(
    const __bf16* __restrict__ A, const __bf16* __restrict__ Bt,
    const float* __restrict__ bias,
    __bf16* __restrict__ Qb, __bf16* __restrict__ Kb, __bf16* __restrict__ Vtb,
    float* __restrict__ Out) {
  __shared__ __bf16 As[128 * 32];
  __shared__ __bf16 Bs[128 * 32];
  const int tid = threadIdx.x;
  const int wave = tid >> 6, lane = tid & 63;
  const int lhi = lane >> 4, llo = lane & 15;
  const int wm = wave >> 1, wn = wave & 1;
  const int m0 = blockIdx.y * 128, n0 = blockIdx.x * 128;

  const int srow = lane >> 2;         // 0..15 within a 16-row issue
  const int scol = (lane & 3) * 8;    // element column (x8 bf16 = 16B)
  const __bf16* Ag0 = A + (size_t)(m0 + (wave * 2 + 0) * 16 + srow) * 1024 + scol;
  const __bf16* Ag1 = A + (size_t)(m0 + (wave * 2 + 1) * 16 + srow) * 1024 + scol;
  const __bf16* Bg0 = Bt + (size_t)(n0 + (wave * 2 + 0) * 16 + srow) * 1024 + scol;
  const __bf16* Bg1 = Bt + (size_t)(n0 + (wave * 2 + 1) * 16 + srow) * 1024 + scol;
  __bf16* As0 = As + (wave * 2 + 0) * 512;
  __bf16* As1 = As + (wave * 2 + 1) * 512;
  __bf16* Bs0 = Bs + (wave * 2 + 0) * 512;
  __bf16* Bs1 = Bs + (wave * 2 + 1) * 512;

  f32x4 acc[4][4];
#pragma unroll
  for (int m = 0; m < 4; ++m)
#pragma unroll
    for (int n = 0; n < 4; ++n) acc[m][n] = (f32x4){0.f, 0.f, 0.f, 0.f};

  for (int k0 = 0; k0 < 1024; k0 += 32) {
    gload_lds16(Ag0 + k0, As0);
    gload_lds16(Ag1 + k0, As1);
    gload_lds16(Bg0 + k0, Bs0);
    gload_lds16(Bg1 + k0, Bs1);
    __syncthreads();
    bf16x8 af[4], bfr[4];
#pragma unroll
    for (int i = 0; i < 4; ++i)
      af[i] = *(const bf16x8*)&As[(wm * 64 + i * 16 + llo) * 32 + lhi * 8];
#pragma unroll
    for (int i = 0; i < 4; ++i)
      bfr[i] = *(const bf16x8*)&Bs[(wn * 64 + i * 16 + llo) * 32 + lhi * 8];
#pragma unroll
    for (int m = 0; m < 4; ++m)
#pragma unroll
      for (int n = 0; n < 4; ++n)
        acc[m][n] = __builtin_amdgcn_mfma_f32_16x16x32_bf16(af[m], bfr[n],
                                                            acc[m][n], 0, 0, 0);
    __syncthreads();
  }

#pragma unroll
  for (int ni = 0; ni < 4; ++ni) {
    const int col = n0 + wn * 64 + ni * 16 + llo;
    const float bv = bias[col];
    if (MODE == 0) {
      const int h = col / 192, rem = col % 192;
#pragma unroll
      for (int mi = 0; mi < 4; ++mi) {
        const int row0 = m0 + wm * 64 + mi * 16 + lhi * 4;
        const int b = row0 >> 11;
        const int s0 = row0 & 2047;
        const int bh = b * 16 + h;
        f32x4 v = acc[mi][ni];
        if (rem < 64) {
#pragma unroll
          for (int r = 0; r < 4; ++r)
            Qb[((size_t)bh * 2048 + s0 + r) * 64 + rem] =
                (__bf16)((v[r] + bv) * 0.125f);
        } else if (rem < 128) {
#pragma unroll
          for (int r = 0; r < 4; ++r)
            Kb[((size_t)bh * 2048 + s0 + r) * 64 + (rem - 64)] = (__bf16)(v[r] + bv);
        } else {
          union { __bf16 h4[4]; int2 v2; } u;
#pragma unroll
          for (int r = 0; r < 4; ++r) u.h4[r] = (__bf16)(v[r] + bv);
          *(int2*)&Vtb[((size_t)bh * 64 + (rem - 128)) * 2048 + s0] = u.v2;
        }
      }
    } else {
#pragma unroll
      for (int mi = 0; mi < 4; ++mi) {
        const int row0 = m0 + wm * 64 + mi * 16 + lhi * 4;
        f32x4 v = acc[mi][ni];
#pragma unroll
        for (int r = 0; r < 4; ++r)
          Out[(size_t)(row0 + r) * 1024 + col] = v[r] + bv;
      }
    }
  }
}

// ---------------------------------------------------------------- attention
// m214-style 8-wave 32x32 structure adapted to hd=64.
// Block: 8 waves x 32 q-rows = 256 q-rows. KV tiles of 64, double-buffered LDS.
// Swapped QK^T: S^T = mfma(K, Q^T)  -> lane holds S[q=lane&31][32 kv vals]
// Swapped PV:   O^T = mfma(V^T, P^T) -> lane-local rescale/normalize.
__global__ __launch_bounds__(512) void attn_kernel(
    const __bf16* __restrict__ Q, const __bf16* __restrict__ K,
    const __bf16* __restrict__ Vt, __bf16* __restrict__ vals) {
  __shared__ __bf16 Ks[2][64 * 64];
  __shared__ __bf16 Vs[2][64 * 64];  // V^T tile: [d=64][kv=64]
  const int tid = threadIdx.x;
  const int wave = tid >> 6, lane = tid & 63;
  const int lq = lane & 31, hi = lane >> 5;

  // XCD-chunked swizzle: XCD x gets bh in [8x, 8x+8); heavy q-blocks first.
  const int wg = blockIdx.x + (blockIdx.y << 3);   // grid (8, 64)
  const int wgid = (wg & 7) * 64 + (wg >> 3);      // bijective (512 % 8 == 0)
  const int bh = wgid >> 3;
  const int qblk = 7 - (wgid & 7);
  const int q0w = qblk * 256 + wave * 32;
  const int nt = 4 * qblk + 4;

  // Q fragments (B-operand of 32x32x16): lane holds Q[q0w+lq][ds*16+hi*8 ..+8]
  bf16x8 qf[4];
  {
    const __bf16* qp = Q + ((size_t)bh * 2048 + q0w + lq) * 64 + hi * 8;
#pragma unroll
    for (int ds = 0; ds < 4; ++ds) qf[ds] = *(const bf16x8*)(qp + ds * 16);
  }

  f32x16 o0, o1;
#pragma unroll
  for (int i = 0; i < 16; ++i) { o0[i] = 0.f; o1[i] = 0.f; }
  float m = -3e38f, l = 0.f;

  // staging: thread -> 16B slot (row, blk), source pre-swizzled (rule #21)
  const int row_s = tid >> 3, blk_s = tid & 7;
  const int sblk = blk_s ^ (row_s & 7);
  const __bf16* Kg = K + ((size_t)bh * 2048 + row_s) * 64 + sblk * 8;
  const __bf16* Vg = Vt + ((size_t)bh * 64 + row_s) * 2048 + sblk * 8;
  __bf16* KsW = &Ks[0][0] + wave * 512;  // wave-uniform LDS base
  __bf16* VsW = &Vs[0][0] + wave * 512;

  // prologue: stage tile 0 into buf 0
  gload_lds16(Kg, KsW);
  gload_lds16(Vg, VsW);
  __syncthreads();

  for (int t = 0; t < nt; ++t) {
    const int kv0 = t * 64;
    const int cur = t & 1, nxt = cur ^ 1;
    if (t + 1 < nt) {
      gload_lds16(Kg + (size_t)(kv0 + 64) * 64, KsW + nxt * 4096);
      gload_lds16(Vg + (kv0 + 64), VsW + nxt * 4096);
    }
    if (kv0 <= q0w + 31) {  // wave-uniform causal skip
      const __bf16* ksb = &Ks[cur][0];
      const __bf16* vsb = &Vs[cur][0];
      const int r0 = lq, r1 = 32 + lq;      // (32+lq)&7 == lq&7
      const int rx = (lq & 7);
      f32x16 s0, s1;
#pragma unroll
      for (int i = 0; i < 16; ++i) { s0[i] = 0.f; s1[i] = 0.f; }
      __builtin_amdgcn_s_setprio(1);
#pragma unroll
      for (int ds = 0; ds < 4; ++ds) {
        const int bb = ((ds * 2 + hi) ^ rx) * 8;
        bf16x8 k0 = *(const bf16x8*)&ksb[r0 * 64 + bb];
        bf16x8 k1 = *(const bf16x8*)&ksb[r1 * 64 + bb];
        s0 = __builtin_amdgcn_mfma_f32_32x32x16_bf16(k0, qf[ds], s0, 0, 0, 0);
        s1 = __builtin_amdgcn_mfma_f32_32x32x16_bf16(k1, qf[ds], s1, 0, 0, 0);
      }
      __builtin_amdgcn_s_setprio(0);

      // causal mask: kv_g > q_g -> -inf (only near/above diagonal)
      const int qg = q0w + lq;
      if (kv0 + 63 > q0w) {
#pragma unroll
        for (int reg = 0; reg < 16; ++reg) {
          const int kvl = (reg & 3) + 8 * (reg >> 2) + 4 * hi;
          if (kv0 + kvl > qg) s0[reg] = -1e30f;
          if (kv0 + 32 + kvl > qg) s1[reg] = -1e30f;
        }
      }
      // lane-local online softmax (row q = lane&31; halves combined via xor-32)
      float mx = s0[0];
#pragma unroll
      for (int i = 1; i < 16; ++i) mx = fmaxf(mx, s0[i]);
#pragma unroll
      for (int i = 0; i < 16; ++i) mx = fmaxf(mx, s1[i]);
      mx = fmaxf(mx, __shfl_xor(mx, 32));
      const float mn = fmaxf(m, mx);
      const float f = __expf(m - mn);
      m = mn;
      float sum = 0.f;
#pragma unroll
      for (int i = 0; i < 16; ++i) { s0[i] = __expf(s0[i] - mn); sum += s0[i]; }
#pragma unroll
      for (int i = 0; i < 16; ++i) { s1[i] = __expf(s1[i] - mn); sum += s1[i]; }
      sum += __shfl_xor(sum, 32);
      l = l * f + sum;
#pragma unroll
      for (int i = 0; i < 16; ++i) { o0[i] *= f; o1[i] *= f; }

      // PV: P repack (cvt_pk + permlane32_swap) -> B-frag; V from LDS as A-frag
#pragma unroll
      for (int ks = 0; ks < 4; ++ks) {
        unsigned pa, pb, pc, pd;
        if (ks < 2) {
          pa = cvt_pk_bf16(s0[ks * 8 + 0], s0[ks * 8 + 1]);
          pb = cvt_pk_bf16(s0[ks * 8 + 2], s0[ks * 8 + 3]);
          pc = cvt_pk_bf16(s0[ks * 8 + 4], s0[ks * 8 + 5]);
          pd = cvt_pk_bf16(s0[ks * 8 + 6], s0[ks * 8 + 7]);
        } else {
          pa = cvt_pk_bf16(s1[(ks - 2) * 8 + 0], s1[(ks - 2) * 8 + 1]);
          pb = cvt_pk_bf16(s1[(ks - 2) * 8 + 2], s1[(ks - 2) * 8 + 3]);
          pc = cvt_pk_bf16(s1[(ks - 2) * 8 + 4], s1[(ks - 2) * 8 + 5]);
          pd = cvt_pk_bf16(s1[(ks - 2) * 8 + 6], s1[(ks - 2) * 8 + 7]);
        }
        asm volatile("v_permlane32_swap_b32 %0, %1" : "+v"(pa), "+v"(pc));
        asm volatile("v_permlane32_swap_b32 %0, %1" : "+v"(pb), "+v"(pd));
        union { unsigned u[4]; bf16x8 v; } pf;
        pf.u[0] = pa; pf.u[1] = pb; pf.u[2] = pc; pf.u[3] = pd;
        const int vb = ((ks * 2 + hi) ^ rx) * 8;
        bf16x8 v0 = *(const bf16x8*)&vsb[r0 * 64 + vb];
        bf16x8 v1 = *(const bf16x8*)&vsb[r1 * 64 + vb];
        o0 = __builtin_amdgcn_mfma_f32_32x32x16_bf16(v0, pf.v, o0, 0, 0, 0);
        o1 = __builtin_amdgcn_mfma_f32_32x32x16_bf16(v1, pf.v, o1, 0, 0, 0);
      }
    }
    __syncthreads();
  }

  // epilogue: normalize (lane-local), pack pairs, swap halves, dword stores
  const float inv = 1.f / l;
#pragma unroll
  for (int i = 0; i < 16; ++i) { o0[i] *= inv; o1[i] *= inv; }
  unsigned* outp = (unsigned*)(vals + ((size_t)bh * 2048 + q0w + lq) * 64);
#pragma unroll
  for (int n = 0; n < 2; ++n) {
#pragma unroll
    for (int g = 0; g < 2; ++g) {
      float e0 = n ? o1[g * 8 + 0] : o0[g * 8 + 0];
      float e1 = n ? o1[g * 8 + 1] : o0[g * 8 + 1];
      float e2 = n ? o1[g * 8 + 2] : o0[g * 8 + 2];
      float e3 = n ? o1[g * 8 + 3] : o0[g * 8 + 3];
      float e4 = n ? o1[g * 8 + 4] : o0[g * 8 + 4];
      float e5 = n ? o1[g * 8 + 5] : o0[g * 8 + 5];
      float e6 = n ? o1[g * 8 + 6] : o0[g * 8 + 6];
      float e7 = n ? o1[g * 8 + 7] : o0[g * 8 + 7];
      unsigned a = cvt_pk_bf16(e0, e1);
      unsigned a2 = cvt_pk_bf16(e2, e3);
      unsigned b = cvt_pk_bf16(e4, e5);
      unsigned b2 = cvt_pk_bf16(e6, e7);
      asm volatile("v_permlane32_swap_b32 %0, %1" : "+v"(a), "+v"(b));
      asm volatile("v_permlane32_swap_b32 %0, %1" : "+v"(a2), "+v"(b2));
      const int dbase = n * 32 + g * 16 + hi * 8;
      outp[(dbase + 0) >> 1] = a;
      outp[(dbase + 2) >> 1] = a2;
      outp[(dbase + 4) >> 1] = b;
      outp[(dbase + 6) >> 1] = b2;
    }
  }
}

// ---------------------------------------------------------------- launch
extern "C" void kernel_launch(void* const* d_in, const int* in_sizes, int n_in,
                              void* d_out, int out_size, void* d_ws, size_t ws_size,
                              hipStream_t stream) {
  const float* x = (const float*)d_in[0];
  const float* Wqkv = (const float*)d_in[1];
  const float* bqkv = (const float*)d_in[2];
  const float* Wo = (const float*)d_in[3];
  const float* bo = (const float*)d_in[4];
  float* out = (float*)d_out;
  char* ws = (char*)d_ws;

  // workspace layout (bytes)
  __bf16* xb  = (__bf16*)(ws);                 // 16 MB (x bf16; reused as vals)
  __bf16* Wqt = (__bf16*)(ws + 16777216);      // 6 MB  (W_qkv^T bf16 [3072][1024])
  __bf16* Wot = (__bf16*)(ws + 23068672);      // 2 MB  (W_o^T bf16 [1024][1024])
  __bf16* Qb  = (__bf16*)(ws + 25165824);      // 16 MB ([BH, S, 64], pre-scaled 1/8)
  __bf16* Kb  = (__bf16*)(ws + 41943040);      // 16 MB ([BH, S, 64])
  __bf16* Vtb = (__bf16*)(ws + 58720256);      // 16 MB ([BH, 64, S])
  __bf16* vals = xb;                           // attention output (scrambled matrix)

  cvt_bf16_kernel<<<4096, 256, 0, stream>>>(x, xb, 1048576);
  cvt_T_kernel<<<dim3(96, 32), 256, 0, stream>>>(Wqkv, Wqt, 1024, 3072);
  cvt_T_kernel<<<dim3(32, 32), 256, 0, stream>>>(Wo, Wot, 1024, 1024);
  gemm_bt<0><<<dim3(24, 64), 256, 0, stream>>>(xb, Wqt, bqkv, Qb, Kb, Vtb, nullptr);
  attn_kernel<<<dim3(8, 64), 512, 0, stream>>>(Qb, Kb, Vtb, vals);
  gemm_bt<1><<<dim3(8, 64), 256, 0, stream>>>(vals, Wot, bo, nullptr, nullptr, nullptr, out);
}